// Round 7
// baseline (223.000 us; speedup 1.0000x reference)
//
#include <hip/hip_runtime.h>

#define HW 256
#define HWHW 65536
#define TOTAL 19296

typedef __attribute__((ext_vector_type(8))) short short8;
typedef __attribute__((ext_vector_type(4))) float float4v;

__device__ inline unsigned bfr(float f) {  // bf16 bits (round half-up), low 16
    return (__builtin_bit_cast(unsigned, f) + 0x8000u) >> 16;
}
__device__ inline float bf2f(unsigned bits) {  // bf16 bits -> f32
    return __builtin_bit_cast(float, bits << 16);
}
__device__ inline unsigned pack2rnd(float lo, float hi) {  // [bf(hi):bf(lo)] via v_perm
    unsigned a = __builtin_bit_cast(unsigned, lo) + 0x8000u;
    unsigned b = __builtin_bit_cast(unsigned, hi) + 0x8000u;
    return __builtin_amdgcn_perm(b, a, 0x07060302u);
}
// async global->LDS, 16B per lane; LDS dest = wave-uniform base + lane*16
__device__ __forceinline__ void gload_lds16(const void* g, void* l) {
    __builtin_amdgcn_global_load_lds(
        (const __attribute__((address_space(1))) unsigned int*)(g),
        (__attribute__((address_space(3))) unsigned int*)(l), 16, 0, 0);
}

// ---------------- MLP: grid (16 jh, 16 b) x 256; K-split layer2, depth 32 ----------------
// r5 decomposition: old 32-block mlp was ~8-12us, latency-bound (256-iter serial chain,
// 12.5% of CUs). Now: 256 blocks; layer1 recomputed per block (16 FMA/thread, trivial);
// layer2 split jl = t&31 (j = jh*32+jl), kc = t>>5 (8 chunks of 32 k); partials reduced
// through LDS. Serial depth 256 -> 32. w1 strip per block 32 KB, L2-resident across b.
__global__ __launch_bounds__(256) void mlp_kernel(
    const float* __restrict__ x_meta, const float* __restrict__ w0, const float* __restrict__ b0,
    const float* __restrict__ w1, const float* __restrict__ b1, float* __restrict__ h1)
{
    int b = blockIdx.y, jh = blockIdx.x, t = threadIdx.x;
    __shared__ float xm[16];
    __shared__ float h0s[256];
    __shared__ float part[256];
    if (t < 16) xm[t] = x_meta[b * 16 + t];
    __syncthreads();
    {
        float a0 = b0[t];
#pragma unroll
        for (int i = 0; i < 16; ++i) a0 += xm[i] * w0[i * 256 + t];
        h0s[t] = fmaxf(a0, 0.f);
    }
    __syncthreads();
    {
        int jl = t & 31, kc = t >> 5;
        int j = jh * 32 + jl;
        const float* wp = w1 + (size_t)(kc * 32) * 512 + j;
        const float* hp = &h0s[kc * 32];
        float acc = 0.f;
#pragma unroll 4
        for (int k = 0; k < 32; ++k) acc += hp[k] * wp[k * 512];
        part[t] = acc;
    }
    __syncthreads();
    if (t < 32) {
        int j = jh * 32 + t;
        float s = b1[j];
#pragma unroll
        for (int kc = 0; kc < 8; ++kc) s += part[kc * 32 + t];
        h1[b * 512 + j] = fmaxf(s, 0.f);
    }
}

// ---------------- flat via MFMA: grid (603) x 256. M=16 b, N=32 j/block, K=512 ----------------
// (unchanged from r5/r6 — measured-neutral structure near its streaming roofline)
__global__ __launch_bounds__(256) void flat_kernel(
    const float* __restrict__ h1, const float* __restrict__ w2, const float* __restrict__ b2,
    float* __restrict__ wc0, unsigned short* __restrict__ wc1, unsigned short* __restrict__ wc2)
{
    __shared__ __align__(16) char fsm[73728];
    unsigned short* whi = (unsigned short*)fsm;
    unsigned short* wlo = (unsigned short*)(fsm + 32768);
    float* red = (float*)(fsm + 65536);

    const int t = threadIdx.x;
    const int lane = t & 63, wave = t >> 6;
    const int l15 = lane & 15, lg = lane >> 4;
    const int j0 = blockIdx.x * 32;           // 603*32 = 19296 exact

    // ---- stage w2 [512k][32j] -> transposed swizzled bf16 hi/lo [j][k] ----
    {
        const int jq = t & 7, kr = t >> 3;
#pragma unroll
        for (int rnd = 0; rnd < 4; ++rnd) {
            float4 v[4];
#pragma unroll
            for (int p = 0; p < 4; ++p) {
                int k = (rnd * 4 + p) * 32 + kr;
                v[p] = *(const float4*)&w2[(size_t)k * TOTAL + j0 + jq * 4];
            }
#pragma unroll
            for (int p = 0; p < 4; ++p) {
                int k = (rnd * 4 + p) * 32 + kr;
#pragma unroll
                for (int i = 0; i < 4; ++i) {
                    float f = (&v[p].x)[i];
                    unsigned hb = bfr(f);
                    unsigned lb = bfr(f - bf2f(hb));
                    int j = jq * 4 + i;
                    int off = (2 * k) ^ ((j & 7) << 4);   // byte offset in row, even
                    whi[(j << 9) + (off >> 1)] = (unsigned short)hb;
                    wlo[(j << 9) + (off >> 1)] = (unsigned short)lb;
                }
            }
        }
    }
    __syncthreads();

    // ---- MFMA: wave w handles k-chunks {w, w+4, w+8, w+12}; 2 j-tiles; 3-term split ----
    float4v acc0 = {0.f, 0.f, 0.f, 0.f}, acc1 = {0.f, 0.f, 0.f, 0.f};
#pragma unroll
    for (int cc = 0; cc < 4; ++cc) {
        const int kc = wave + cc * 4;         // 0..15
        const float* hp = h1 + l15 * 512 + kc * 32 + lg * 8;
        float4 h0v = *(const float4*)hp;
        float4 h1v = *(const float4*)(hp + 4);
        uint4 Hh, Hl;
        Hh.x = pack2rnd(h0v.x, h0v.y); Hh.y = pack2rnd(h0v.z, h0v.w);
        Hh.z = pack2rnd(h1v.x, h1v.y); Hh.w = pack2rnd(h1v.z, h1v.w);
        float r0 = h0v.x - bf2f(bfr(h0v.x)), r1 = h0v.y - bf2f(bfr(h0v.y));
        float r2 = h0v.z - bf2f(bfr(h0v.z)), r3 = h0v.w - bf2f(bfr(h0v.w));
        float r4 = h1v.x - bf2f(bfr(h1v.x)), r5 = h1v.y - bf2f(bfr(h1v.y));
        float r6 = h1v.z - bf2f(bfr(h1v.z)), r7 = h1v.w - bf2f(bfr(h1v.w));
        Hl.x = pack2rnd(r0, r1); Hl.y = pack2rnd(r2, r3);
        Hl.z = pack2rnd(r4, r5); Hl.w = pack2rnd(r6, r7);
        short8 Bhi = __builtin_bit_cast(short8, Hh);
        short8 Blo = __builtin_bit_cast(short8, Hl);
#pragma unroll
        for (int tt = 0; tt < 2; ++tt) {
            int jr = tt * 16 + l15;
            int boff = (jr << 10) + (((kc << 6) + (lg << 4)) ^ ((jr & 7) << 4));
            short8 Ahi = *(const short8*)((const char*)whi + boff);
            short8 Alo = *(const short8*)((const char*)wlo + boff);
            float4v a = tt ? acc1 : acc0;
            a = __builtin_amdgcn_mfma_f32_16x16x32_bf16(Ahi, Bhi, a, 0, 0, 0);
            a = __builtin_amdgcn_mfma_f32_16x16x32_bf16(Ahi, Blo, a, 0, 0, 0);
            a = __builtin_amdgcn_mfma_f32_16x16x32_bf16(Alo, Bhi, a, 0, 0, 0);
            if (tt) acc1 = a; else acc0 = a;
        }
    }
    *(float4v*)&red[(((wave * 2 + 0) * 64 + lane) << 2)] = acc0;
    *(float4v*)&red[(((wave * 2 + 1) * 64 + lane) << 2)] = acc1;
    __syncthreads();

    // ---- reduce over 4 waves + bias + relu + scatter (mapping verbatim from r4) ----
#pragma unroll
    for (int half = 0; half < 2; ++half) {
        int idx = t + half * 256;             // 0..511 = 2 tiles x 256 elems
        int tt = idx >> 8, rem = idx & 255, ln = rem >> 2, r = rem & 3;
        float s = 0.f;
#pragma unroll
        for (int w = 0; w < 4; ++w) s += red[(((w * 2 + tt) * 64 + ln) << 2) + r];
        int b = ln & 15;                                   // D col = batch
        int j = j0 + tt * 16 + ((ln >> 4) << 2) + r;       // D row = j-in-tile
        float v = fmaxf(s + b2[j], 0.f);
        if (j < 288) {
            wc0[b * 288 + j] = v;
        } else if (j < 18720) {
            int rr = j - 288;
            int oc = rr / 288; int rem2 = rr - oc * 288;
            int ic = rem2 / 9;  int tap = rem2 - ic * 9;
            wc1[(((b * 9 + tap) * 64 + oc) << 5) + ic] = (unsigned short)bfr(v);
        } else {
            int rr = j - 18720;
            int ic = rr / 9; int tap = rr - ic * 9;
            int mt = ic >> 4, lgp = (ic >> 2) & 3, reg = ic & 3;
            int kperm = ((mt >> 1) << 5) + (lgp << 3) + ((mt & 1) << 2) + reg;
            wc2[(b * 9 + tap) * 64 + kperm] = (unsigned short)bfr(v);
        }
    }
}

// ---------------- fused conv0+conv1+conv2: one 16x16 output tile per 512-thread block ----------------
// r6 cycle model: LDS pipe ~75% busy (530 b128 reads/block) = bottleneck; only 2 blocks/CU
// (16 waves) to cover its latency gaps. This round: wc1s 36KB -> 2-SLOT RING (8KB, 4KB/tap):
// prologue stages taps 0,1; per tap: compute(slot t&1) -> __syncthreads (implicit vmcnt(0)
// drain retires in-flight stage; also frees slot) -> waves 0-3 issue gload_lds(tap+2 -> slot
// t&1). Stage completes at the NEXT barrier's drain, one tap before first read. LDS 52992
// (alloc 53248) -> 3 blocks/CU (159744 <= 163840), 24 waves. __launch_bounds__(512,6) = 3
// blocks/CU; VGPR cap ~85, kernel at ~52 — safe (r8 catastrophe was a ~116-VGPR kernel).
//   b0s  [400 px][32 sh, 64 B stride, XOR 16B groups g^((px>>1)&3)] @0      (25600 B)
//   xtb  [400 px][24 sh, 48 B stride] im2col conv0-B @25600 (19200 B)
//   pbuf [324][13] f32 @25600 (16848 B, aliases dead xtb — barrier 2 orders)
//   wc1s 2-slot ring [2][64 oc][32 ic] bf16, XOR-swizzled @44800 (8192 B)
// Swizzle via rule-#21: LINEAR LDS dest + INVERSE-swizzled per-lane global source chunk
// c=(n&~3)|((n&3)^((n>>3)&3)) (in-tap, 256-chunk aligned so tap bits unaffected), swizzled
// conv1 read slot = lg^((r>>1)&3) -> conflict-free ds_read_b128.
// conv1 C feeds conv2 B DIRECTLY from registers (wc2 k-order permuted by flat_kernel).
__global__ __launch_bounds__(512, 6) void fused_conv_kernel(
    const float* __restrict__ x, const float* __restrict__ wc0,
    const unsigned short* __restrict__ wc1, const unsigned short* __restrict__ wc2,
    float* __restrict__ out)
{
    __shared__ __align__(16) char smem[52992];
    short* b0s  = (short*)smem;
    short* xtb  = (short*)(smem + 25600);
    float* pbuf = (float*)(smem + 25600);   // aliases xtb (dead after barrier 2)
    char*  wc1s = smem + 44800;             // 2-slot ring, 4096 B per tap

    const int t = threadIdx.x;
    const int bx = blockIdx.x, b = blockIdx.y;
    const int x0 = (bx & 15) << 4, y0 = (bx >> 4) << 4;
    const int lane = t & 63, wave = t >> 6;
    const int l15 = lane & 15, lg = lane >> 4;
    const float* xb = x + (size_t)b * HWHW;
    const char* wgb = (const char*)(wc1 + (size_t)b * 18432);

    // ---- prologue: stage taps 0,1 into slots 0,1 (8 wave-insts, 1 per wave) ----
    {
        int n_full = (wave << 6) | lane;                  // 0..511 over taps 0-1
        int n = n_full & 255;                             // in-tap dest chunk
        int c = (n & ~3) | ((n & 3) ^ ((n >> 3) & 3));    // pre-swizzled source chunk
        int tap = n_full >> 8;
        gload_lds16(wgb + (tap * 256 + c) * 16, wc1s + tap * 4096 + n * 16);
    }

    // ---- A-fragment global loads (latency overlapped with xtb build) ----
    short8 A0, A1;
    {
        short8 z = {0,0,0,0,0,0,0,0};
        A0 = z; A1 = z;
        const float* wbase = wc0 + b * 288;
#pragma unroll
        for (int mt = 0; mt < 2; ++mt) {
            const float* wp = wbase + (mt * 16 + l15) * 9;
            short8 a = z;
            if (lg == 0) {
                uint4 pk;
                pk.x = pack2rnd(wp[0], wp[1]);
                pk.y = pack2rnd(wp[2], wp[3]);
                pk.z = pack2rnd(wp[4], wp[5]);
                pk.w = pack2rnd(wp[6], wp[7]);
                a = __builtin_bit_cast(short8, pk);
            } else if (lg == 1) {
                a[0] = (short)bfr(wp[8]);
            }
            if (mt == 0) A0 = a; else A1 = a;
        }
    }
    // conv2 A (permuted k-order, contiguous): A[m=tap][k], rows 9..15 zero
    short8 A2[2];
#pragma unroll
    for (int kc = 0; kc < 2; ++kc) {
        int tp = l15 < 9 ? l15 : 0;
        short8 v = *(const short8*)(wc2 + b * 576 + kc * 32 + tp * 64 + lg * 8);
        short8 z = {0, 0, 0, 0, 0, 0, 0, 0};
        A2[kc] = (l15 < 9) ? v : z;
    }

    // ---- xtb im2col build: 400 px (20x20 halo), 9 bf16 taps + zero pad; zeros if px OOB ----
    if (t < 400) {
        int r0 = t / 20, c0 = t - r0 * 20;
        int gy = y0 - 2 + r0, gx = x0 - 2 + c0;
        bool vis = ((unsigned)gy < (unsigned)HW) && ((unsigned)gx < (unsigned)HW);
        int cy[3], cxv[3]; bool oy[3], ox[3];
#pragma unroll
        for (int d = 0; d < 3; ++d) {
            int Y = gy - 1 + d; oy[d] = ((unsigned)Y < (unsigned)HW); cy[d] = oy[d] ? Y : 0;
            int X = gx - 1 + d; ox[d] = ((unsigned)X < (unsigned)HW); cxv[d] = ox[d] ? X : 0;
        }
        float v[9];
#pragma unroll
        for (int k = 0; k < 9; ++k) {
            int ky = k / 3, kx = k - ky * 3;
            float lv = xb[cy[ky] * HW + cxv[kx]];
            v[k] = (vis && oy[ky] && ox[kx]) ? lv : 0.f;
        }
        uint4 q0, q1;
        q0.x = pack2rnd(v[0], v[1]); q0.y = pack2rnd(v[2], v[3]);
        q0.z = pack2rnd(v[4], v[5]); q0.w = pack2rnd(v[6], v[7]);
        q1.x = pack2rnd(v[8], 0.f);  q1.y = 0; q1.z = 0; q1.w = 0;
        char* d = (char*)xtb + t * 48;
        *(uint4*)d = q0;
        *(uint4*)(d + 16) = q1;
    }
    __syncthreads();   // 1  (drains vmcnt: slots 0,1 + xtb complete)

    // ---- conv0 via MFMA: N=400 px in 25 groups over 8 waves; B from xtb (zero-padded) ----
    for (int g = wave; g < 25; g += 8) {
        int px = g * 16 + l15;                 // 0..399
        short8 Bf = {0,0,0,0,0,0,0,0};
        if (lg < 2) Bf = *(const short8*)((const char*)xtb + px * 48 + lg * 16);
        float4v zz = {0.f, 0.f, 0.f, 0.f};
        float4v d0 = __builtin_amdgcn_mfma_f32_16x16x32_bf16(A0, Bf, zz, 0, 0, 0);
        float4v d1 = __builtin_amdgcn_mfma_f32_16x16x32_bf16(A1, Bf, zz, 0, 0, 0);
        uint2 wv0, wv1;
        wv0.x = pack2rnd(d0[0], d0[1]); wv0.y = pack2rnd(d0[2], d0[3]);
        wv1.x = pack2rnd(d1[0], d1[1]); wv1.y = pack2rnd(d1[2], d1[3]);
        int psw = (px >> 1) & 3;
        char* base = (char*)b0s + px * 64 + ((lg & 1) << 3);
        *(uint2*)(base + ((((lg >> 1)    ) ^ psw) << 4)) = wv0;
        *(uint2*)(base + ((((lg >> 1) + 2) ^ psw) << 4)) = wv1;
    }
    __syncthreads();   // 2

    // ---- conv1: 21 groups of 16 px over 18x18; 3 slots per wave; A from wc1s ring ----
    int  p2c[3];
    int  pxb[3];   // b0s px index (20x20 domain) for tap 0
    bool inb[3];
#pragma unroll
    for (int i = 0; i < 3; ++i) {
        int g = wave + i * 8;
        if (g < 21) {
            int p2 = g * 16 + l15;
            int pc = p2 > 323 ? 323 : p2;
            p2c[i] = pc;
            int r2 = pc / 18, c2 = pc - r2 * 18;
            pxb[i] = r2 * 20 + c2;
            int gy1 = y0 - 1 + r2, gx1 = x0 - 1 + c2;
            inb[i] = (gy1 >= 0 && gy1 < HW && gx1 >= 0 && gx1 < HW);
        }
    }
    float4v acc1[3][4];
#pragma unroll
    for (int i = 0; i < 3; ++i)
#pragma unroll
        for (int mt = 0; mt < 4; ++mt) acc1[i][mt] = (float4v){0.f, 0.f, 0.f, 0.f};

    const int aoff = l15 * 64 + ((lg ^ ((l15 >> 1) & 3)) << 4);   // swizzled A-frag offset
#pragma unroll
    for (int tap = 0; tap < 9; ++tap) {
        const int ky = tap / 3, kx = tap - (tap / 3) * 3;
        const int po = ky * 20 + kx;
        short8 A[4];
#pragma unroll
        for (int mt = 0; mt < 4; ++mt)
            A[mt] = *(const short8*)(wc1s + (tap & 1) * 4096 + mt * 1024 + aoff);
#pragma unroll
        for (int i = 0; i < 3; ++i) {
            int g = wave + i * 8;
            if (g < 21) {
                int px20 = pxb[i] + po;
                short8 Bf = *(const short8*)((const char*)b0s + px20 * 64 +
                                             ((lg ^ ((px20 >> 1) & 3)) << 4));
#pragma unroll
                for (int mt = 0; mt < 4; ++mt)
                    acc1[i][mt] = __builtin_amdgcn_mfma_f32_16x16x32_bf16(A[mt], Bf, acc1[i][mt], 0, 0, 0);
            }
        }
        // ring maintenance: free slot tap&1, then stage tap+2 into it (waves 0-3).
        // Barrier needed after taps 0..7 (protect slot before overwrite / drain prior stage).
        if (tap < 8) {
            __syncthreads();                       // all reads of slot tap&1 done + vmcnt drain
            if (tap + 2 <= 8 && wave < 4) {
                int n = (wave << 6) | lane;        // 0..255 in-tap dest chunk
                int c = (n & ~3) | ((n & 3) ^ ((n >> 3) & 3));
                gload_lds16(wgb + ((tap + 2) * 256 + c) * 16,
                            wc1s + (tap & 1) * 4096 + n * 16);
            }
        }
    }

    // ---- conv2 in-register: B-frag[kc] = bf16(acc1[2kc], acc1[2kc+1]); D[m=tap][n=px] ----
#pragma unroll
    for (int i = 0; i < 3; ++i) {
        int g = wave + i * 8;
        if (g < 21) {
            int pc = p2c[i];
            float4v acc2 = (float4v){0.f, 0.f, 0.f, 0.f};
#pragma unroll
            for (int kc = 0; kc < 2; ++kc) {
                uint4 dv;
                dv.x = pack2rnd(acc1[i][kc * 2][0],     acc1[i][kc * 2][1]);
                dv.y = pack2rnd(acc1[i][kc * 2][2],     acc1[i][kc * 2][3]);
                dv.z = pack2rnd(acc1[i][kc * 2 + 1][0], acc1[i][kc * 2 + 1][1]);
                dv.w = pack2rnd(acc1[i][kc * 2 + 1][2], acc1[i][kc * 2 + 1][3]);
                if (!inb[i]) { dv.x = 0; dv.y = 0; dv.z = 0; dv.w = 0; }
                short8 Bf = __builtin_bit_cast(short8, dv);
                acc2 = __builtin_amdgcn_mfma_f32_16x16x32_bf16(A2[kc], Bf, acc2, 0, 0, 0);
            }
            if (lg < 2) {
#pragma unroll
                for (int u = 0; u < 4; ++u) pbuf[pc * 13 + lg * 4 + u] = acc2[u];
            } else if (lg == 2) {
                pbuf[pc * 13 + 8] = acc2[0];
            }
        }
    }
    __syncthreads();   // 3

    // ---- reduction: out(r,c) = sum_tap pbuf[(r+ky)*18 + (c+kx)][tap] ----
    if (t < 256) {
        int r = t >> 4, c = t & 15;
        float o = 0.f;
#pragma unroll
        for (int ky = 0; ky < 3; ++ky)
#pragma unroll
            for (int kx = 0; kx < 3; ++kx)
                o += pbuf[((r + ky) * 18 + (c + kx)) * 13 + (ky * 3 + kx)];
        out[(size_t)b * HWHW + (y0 + r) * HW + (x0 + c)] = o;
    }
}

extern "C" void kernel_launch(void* const* d_in, const int* in_sizes, int n_in,
                              void* d_out, int out_size, void* d_ws, size_t ws_size,
                              hipStream_t stream)
{
    const float* x_meta = (const float*)d_in[0];
    const float* x      = (const float*)d_in[1];
    const float* w0     = (const float*)d_in[2];
    const float* b0     = (const float*)d_in[3];
    const float* w1     = (const float*)d_in[4];
    const float* b1     = (const float*)d_in[5];
    const float* w2     = (const float*)d_in[6];
    const float* b2     = (const float*)d_in[7];
    float* out = (float*)d_out;

    char* ws = (char*)d_ws;
    float* h1 = (float*)ws;                                                // @0       32768 B
    float* wc0 = (float*)(ws + 32768);                                     // @32768   18432 B
    unsigned short* wc1 = (unsigned short*)(ws + 51200);                   // @51200   589824 B
    unsigned short* wc2 = (unsigned short*)(ws + 641024);                  // @641024  18432 B

    mlp_kernel<<<dim3(16, 16), 256, 0, stream>>>(x_meta, w0, b0, w1, b1, h1);
    flat_kernel<<<603, 256, 0, stream>>>(h1, w2, b2, wc0, wc1, wc2);
    fused_conv_kernel<<<dim3(256, 16), 512, 0, stream>>>(x, wc0, wc1, wc2, out);
}

// Round 8
// 164.165 us; speedup vs baseline: 1.3584x; 1.3584x over previous
//
#include <hip/hip_runtime.h>

#define HW 256
#define HWHW 65536
#define TOTAL 19296

typedef __attribute__((ext_vector_type(8))) short short8;
typedef __attribute__((ext_vector_type(4))) float float4v;

__device__ inline unsigned bfr(float f) {  // bf16 bits (round half-up), low 16
    return (__builtin_bit_cast(unsigned, f) + 0x8000u) >> 16;
}
__device__ inline float bf2f(unsigned bits) {  // bf16 bits -> f32
    return __builtin_bit_cast(float, bits << 16);
}
__device__ inline unsigned pack2rnd(float lo, float hi) {  // [bf(hi):bf(lo)] via v_perm
    unsigned a = __builtin_bit_cast(unsigned, lo) + 0x8000u;
    unsigned b = __builtin_bit_cast(unsigned, hi) + 0x8000u;
    return __builtin_amdgcn_perm(b, a, 0x07060302u);
}
// async global->LDS, 16B per lane; LDS dest = wave-uniform base + lane*16
__device__ __forceinline__ void gload_lds16(const void* g, void* l) {
    __builtin_amdgcn_global_load_lds(
        (const __attribute__((address_space(1))) unsigned int*)(g),
        (__attribute__((address_space(3))) unsigned int*)(l), 16, 0, 0);
}

// ---------------- MLP: grid (16 jh, 16 b) x 256; K-split layer2, depth 32 ----------------
// r5 decomposition: old 32-block mlp was ~8-12us, latency-bound (256-iter serial chain,
// 12.5% of CUs). Now: 256 blocks; layer1 recomputed per block (16 FMA/thread, trivial);
// layer2 split jl = t&31 (j = jh*32+jl), kc = t>>5 (8 chunks of 32 k); partials reduced
// through LDS. Serial depth 256 -> 32. Measured r6: total -11.8us vs r5's mlp.
__global__ __launch_bounds__(256) void mlp_kernel(
    const float* __restrict__ x_meta, const float* __restrict__ w0, const float* __restrict__ b0,
    const float* __restrict__ w1, const float* __restrict__ b1, float* __restrict__ h1)
{
    int b = blockIdx.y, jh = blockIdx.x, t = threadIdx.x;
    __shared__ float xm[16];
    __shared__ float h0s[256];
    __shared__ float part[256];
    if (t < 16) xm[t] = x_meta[b * 16 + t];
    __syncthreads();
    {
        float a0 = b0[t];
#pragma unroll
        for (int i = 0; i < 16; ++i) a0 += xm[i] * w0[i * 256 + t];
        h0s[t] = fmaxf(a0, 0.f);
    }
    __syncthreads();
    {
        int jl = t & 31, kc = t >> 5;
        int j = jh * 32 + jl;
        const float* wp = w1 + (size_t)(kc * 32) * 512 + j;
        const float* hp = &h0s[kc * 32];
        float acc = 0.f;
#pragma unroll 4
        for (int k = 0; k < 32; ++k) acc += hp[k] * wp[k * 512];
        part[t] = acc;
    }
    __syncthreads();
    if (t < 32) {
        int j = jh * 32 + t;
        float s = b1[j];
#pragma unroll
        for (int kc = 0; kc < 8; ++kc) s += part[kc * 32 + t];
        h1[b * 512 + j] = fmaxf(s, 0.f);
    }
}

// ---------------- flat via MFMA: grid (603) x 256. M=16 b, N=32 j/block, K=512 ----------------
// (unchanged from r5/r6 — measured structure near its streaming roofline)
__global__ __launch_bounds__(256) void flat_kernel(
    const float* __restrict__ h1, const float* __restrict__ w2, const float* __restrict__ b2,
    float* __restrict__ wc0, unsigned short* __restrict__ wc1, unsigned short* __restrict__ wc2)
{
    __shared__ __align__(16) char fsm[73728];
    unsigned short* whi = (unsigned short*)fsm;
    unsigned short* wlo = (unsigned short*)(fsm + 32768);
    float* red = (float*)(fsm + 65536);

    const int t = threadIdx.x;
    const int lane = t & 63, wave = t >> 6;
    const int l15 = lane & 15, lg = lane >> 4;
    const int j0 = blockIdx.x * 32;           // 603*32 = 19296 exact

    // ---- stage w2 [512k][32j] -> transposed swizzled bf16 hi/lo [j][k] ----
    {
        const int jq = t & 7, kr = t >> 3;
#pragma unroll
        for (int rnd = 0; rnd < 4; ++rnd) {
            float4 v[4];
#pragma unroll
            for (int p = 0; p < 4; ++p) {
                int k = (rnd * 4 + p) * 32 + kr;
                v[p] = *(const float4*)&w2[(size_t)k * TOTAL + j0 + jq * 4];
            }
#pragma unroll
            for (int p = 0; p < 4; ++p) {
                int k = (rnd * 4 + p) * 32 + kr;
#pragma unroll
                for (int i = 0; i < 4; ++i) {
                    float f = (&v[p].x)[i];
                    unsigned hb = bfr(f);
                    unsigned lb = bfr(f - bf2f(hb));
                    int j = jq * 4 + i;
                    int off = (2 * k) ^ ((j & 7) << 4);   // byte offset in row, even
                    whi[(j << 9) + (off >> 1)] = (unsigned short)hb;
                    wlo[(j << 9) + (off >> 1)] = (unsigned short)lb;
                }
            }
        }
    }
    __syncthreads();

    // ---- MFMA: wave w handles k-chunks {w, w+4, w+8, w+12}; 2 j-tiles; 3-term split ----
    float4v acc0 = {0.f, 0.f, 0.f, 0.f}, acc1 = {0.f, 0.f, 0.f, 0.f};
#pragma unroll
    for (int cc = 0; cc < 4; ++cc) {
        const int kc = wave + cc * 4;         // 0..15
        const float* hp = h1 + l15 * 512 + kc * 32 + lg * 8;
        float4 h0v = *(const float4*)hp;
        float4 h1v = *(const float4*)(hp + 4);
        uint4 Hh, Hl;
        Hh.x = pack2rnd(h0v.x, h0v.y); Hh.y = pack2rnd(h0v.z, h0v.w);
        Hh.z = pack2rnd(h1v.x, h1v.y); Hh.w = pack2rnd(h1v.z, h1v.w);
        float r0 = h0v.x - bf2f(bfr(h0v.x)), r1 = h0v.y - bf2f(bfr(h0v.y));
        float r2 = h0v.z - bf2f(bfr(h0v.z)), r3 = h0v.w - bf2f(bfr(h0v.w));
        float r4 = h1v.x - bf2f(bfr(h1v.x)), r5 = h1v.y - bf2f(bfr(h1v.y));
        float r6 = h1v.z - bf2f(bfr(h1v.z)), r7 = h1v.w - bf2f(bfr(h1v.w));
        Hl.x = pack2rnd(r0, r1); Hl.y = pack2rnd(r2, r3);
        Hl.z = pack2rnd(r4, r5); Hl.w = pack2rnd(r6, r7);
        short8 Bhi = __builtin_bit_cast(short8, Hh);
        short8 Blo = __builtin_bit_cast(short8, Hl);
#pragma unroll
        for (int tt = 0; tt < 2; ++tt) {
            int jr = tt * 16 + l15;
            int boff = (jr << 10) + (((kc << 6) + (lg << 4)) ^ ((jr & 7) << 4));
            short8 Ahi = *(const short8*)((const char*)whi + boff);
            short8 Alo = *(const short8*)((const char*)wlo + boff);
            float4v a = tt ? acc1 : acc0;
            a = __builtin_amdgcn_mfma_f32_16x16x32_bf16(Ahi, Bhi, a, 0, 0, 0);
            a = __builtin_amdgcn_mfma_f32_16x16x32_bf16(Ahi, Blo, a, 0, 0, 0);
            a = __builtin_amdgcn_mfma_f32_16x16x32_bf16(Alo, Bhi, a, 0, 0, 0);
            if (tt) acc1 = a; else acc0 = a;
        }
    }
    *(float4v*)&red[(((wave * 2 + 0) * 64 + lane) << 2)] = acc0;
    *(float4v*)&red[(((wave * 2 + 1) * 64 + lane) << 2)] = acc1;
    __syncthreads();

    // ---- reduce over 4 waves + bias + relu + scatter (mapping verbatim from r4) ----
#pragma unroll
    for (int half = 0; half < 2; ++half) {
        int idx = t + half * 256;             // 0..511 = 2 tiles x 256 elems
        int tt = idx >> 8, rem = idx & 255, ln = rem >> 2, r = rem & 3;
        float s = 0.f;
#pragma unroll
        for (int w = 0; w < 4; ++w) s += red[(((w * 2 + tt) * 64 + ln) << 2) + r];
        int b = ln & 15;                                   // D col = batch
        int j = j0 + tt * 16 + ((ln >> 4) << 2) + r;       // D row = j-in-tile
        float v = fmaxf(s + b2[j], 0.f);
        if (j < 288) {
            wc0[b * 288 + j] = v;
        } else if (j < 18720) {
            int rr = j - 288;
            int oc = rr / 288; int rem2 = rr - oc * 288;
            int ic = rem2 / 9;  int tap = rem2 - ic * 9;
            wc1[(((b * 9 + tap) * 64 + oc) << 5) + ic] = (unsigned short)bfr(v);
        } else {
            int rr = j - 18720;
            int ic = rr / 9; int tap = rr - ic * 9;
            int mt = ic >> 4, lgp = (ic >> 2) & 3, reg = ic & 3;
            int kperm = ((mt >> 1) << 5) + (lgp << 3) + ((mt & 1) << 2) + reg;
            wc2[(b * 9 + tap) * 64 + kperm] = (unsigned short)bfr(v);
        }
    }
}

// ---------------- fused conv0+conv1+conv2: one 16x16 output tile per 512-thread block ----------------
// __launch_bounds__(512,4): VGPR cap 128. DO NOT RAISE THE WAVE BOUND: (512,6) caps the
// unified VGPR/AGPR file at ~85/wave; this kernel needs ~116 (52 arch + 48 acc1 + operands)
// -> compiler demotes MFMA accumulators to scratch. TWICE-MEASURED catastrophe: prior-session
// r8, and this-session r7 (dur 66->127us, WRITE_SIZE 4->181MB, FETCH +41MB, VGPR_Count 52->40).
// 3 blocks/CU is register-infeasible; occupancy lever is CLOSED. r3's reg-staged wc1 was the
// same failure mode at (512,4) (WRITE 4->130MB) — fixed by global_load_lds (zero VGPR cost).
// LDS 81664 B (alloc 81920) -> 2 blocks/CU:
//   b0s  [400 px][32 sh, 64 B stride, XOR 16B groups g^((px>>1)&3)] @0      (25600 B)
//   xtb  [400 px][24 sh, 48 B stride] im2col conv0-B (taps 0..8, pad 0) @25600 (19200 B)
//   pbuf [324][13] f32 @25600 (16848 B, aliases dead xtb — barrier 2 orders)
//   wc1s [9 tap][64 oc][32 ic] bf16, 16B slots XOR-swizzled @44800 (36864 B)
// Swizzle via rule-#21 both-sides pattern: LINEAR LDS dest (gload_lds writes base+lane*16),
// INVERSE-swizzled per-lane global source chunk c=(n&~3)|((n&3)^((n>>3)&3)) (XOR involution),
// swizzled conv1 read slot = lg^((r>>1)&3). Gang-of-8 lanes hit banks {0,4,1,5,2,6,3,7}
// -> conflict-free ds_read_b128.
// conv1 C feeds conv2 B DIRECTLY from registers: conv2's k-order is permuted (see flat_kernel)
// so B-frag[kc] = pack_bf16(acc1[2kc][0..3], acc1[2kc+1][0..3]) — no LDS transpose, no b1s.
// Profile state (r5/r6, stable): 66us, MfmaUtil ~35 + VALUBusy ~52 = 87% issue; LDS pipe ~75%
// busy (530 b128 reads/block) = bottleneck pipe; 3-pipe balanced, within ~15-20% of this
// structure's limit. Costed-and-rejected: 32x32 MFMA (324px tiling waste), bigger tiles (LDS),
// kernel split (>=384MB intermediate traffic vs 15MB fused), fewer LDS reads (none found <477).
__global__ __launch_bounds__(512, 4) void fused_conv_kernel(
    const float* __restrict__ x, const float* __restrict__ wc0,
    const unsigned short* __restrict__ wc1, const unsigned short* __restrict__ wc2,
    float* __restrict__ out)
{
    __shared__ __align__(16) char smem[81664];
    short* b0s  = (short*)smem;
    short* xtb  = (short*)(smem + 25600);
    float* pbuf = (float*)(smem + 25600);   // aliases xtb (dead after barrier 2)
    char*  wc1s = smem + 44800;

    const int t = threadIdx.x;
    const int bx = blockIdx.x, b = blockIdx.y;
    const int x0 = (bx & 15) << 4, y0 = (bx >> 4) << 4;
    const int lane = t & 63, wave = t >> 6;
    const int l15 = lane & 15, lg = lane >> 4;
    const float* xb = x + (size_t)b * HWHW;

    // ---- wc1 -> LDS via global_load_lds: 2304 16B chunks = 36 wave-insts over 8 waves ----
    {
        const char* wgb = (const char*)(wc1 + (size_t)b * 18432);
        for (int inst = wave; inst < 36; inst += 8) {
            int n = (inst << 6) | lane;                       // dest LDS chunk
            int c = (n & ~3) | ((n & 3) ^ ((n >> 3) & 3));    // pre-swizzled source chunk
            gload_lds16(wgb + c * 16, wc1s + inst * 1024);
        }
    }

    // ---- A-fragment global loads (latency overlapped with xtb build) ----
    short8 A0, A1;
    {
        short8 z = {0,0,0,0,0,0,0,0};
        A0 = z; A1 = z;
        const float* wbase = wc0 + b * 288;
#pragma unroll
        for (int mt = 0; mt < 2; ++mt) {
            const float* wp = wbase + (mt * 16 + l15) * 9;
            short8 a = z;
            if (lg == 0) {
                uint4 pk;
                pk.x = pack2rnd(wp[0], wp[1]);
                pk.y = pack2rnd(wp[2], wp[3]);
                pk.z = pack2rnd(wp[4], wp[5]);
                pk.w = pack2rnd(wp[6], wp[7]);
                a = __builtin_bit_cast(short8, pk);
            } else if (lg == 1) {
                a[0] = (short)bfr(wp[8]);
            }
            if (mt == 0) A0 = a; else A1 = a;
        }
    }
    // conv2 A (permuted k-order, contiguous): A[m=tap][k], rows 9..15 zero
    short8 A2[2];
#pragma unroll
    for (int kc = 0; kc < 2; ++kc) {
        int tp = l15 < 9 ? l15 : 0;
        short8 v = *(const short8*)(wc2 + b * 576 + kc * 32 + tp * 64 + lg * 8);
        short8 z = {0, 0, 0, 0, 0, 0, 0, 0};
        A2[kc] = (l15 < 9) ? v : z;
    }

    // ---- xtb im2col build: 400 px (20x20 halo), 9 bf16 taps + zero pad; zeros if px OOB ----
    if (t < 400) {
        int r0 = t / 20, c0 = t - r0 * 20;
        int gy = y0 - 2 + r0, gx = x0 - 2 + c0;
        bool vis = ((unsigned)gy < (unsigned)HW) && ((unsigned)gx < (unsigned)HW);
        int cy[3], cxv[3]; bool oy[3], ox[3];
#pragma unroll
        for (int d = 0; d < 3; ++d) {
            int Y = gy - 1 + d; oy[d] = ((unsigned)Y < (unsigned)HW); cy[d] = oy[d] ? Y : 0;
            int X = gx - 1 + d; ox[d] = ((unsigned)X < (unsigned)HW); cxv[d] = ox[d] ? X : 0;
        }
        float v[9];
#pragma unroll
        for (int k = 0; k < 9; ++k) {
            int ky = k / 3, kx = k - ky * 3;
            float lv = xb[cy[ky] * HW + cxv[kx]];
            v[k] = (vis && oy[ky] && ox[kx]) ? lv : 0.f;
        }
        uint4 q0, q1;
        q0.x = pack2rnd(v[0], v[1]); q0.y = pack2rnd(v[2], v[3]);
        q0.z = pack2rnd(v[4], v[5]); q0.w = pack2rnd(v[6], v[7]);
        q1.x = pack2rnd(v[8], 0.f);  q1.y = 0; q1.z = 0; q1.w = 0;
        char* d = (char*)xtb + t * 48;
        *(uint4*)d = q0;
        *(uint4*)(d + 16) = q1;
    }
    __syncthreads();   // 1  (drains vmcnt: wc1s + xtb complete)

    // ---- conv0 via MFMA: N=400 px in 25 groups over 8 waves; B from xtb (zero-padded) ----
    for (int g = wave; g < 25; g += 8) {
        int px = g * 16 + l15;                 // 0..399
        short8 Bf = {0,0,0,0,0,0,0,0};
        if (lg < 2) Bf = *(const short8*)((const char*)xtb + px * 48 + lg * 16);
        float4v zz = {0.f, 0.f, 0.f, 0.f};
        float4v d0 = __builtin_amdgcn_mfma_f32_16x16x32_bf16(A0, Bf, zz, 0, 0, 0);
        float4v d1 = __builtin_amdgcn_mfma_f32_16x16x32_bf16(A1, Bf, zz, 0, 0, 0);
        uint2 wv0, wv1;
        wv0.x = pack2rnd(d0[0], d0[1]); wv0.y = pack2rnd(d0[2], d0[3]);
        wv1.x = pack2rnd(d1[0], d1[1]); wv1.y = pack2rnd(d1[2], d1[3]);
        // b0s write: chunk c = lg (wv0) / 4+lg (wv1); group = c>>1 ^ ((px>>1)&3); inner = lg&1
        int psw = (px >> 1) & 3;
        char* base = (char*)b0s + px * 64 + ((lg & 1) << 3);
        *(uint2*)(base + ((((lg >> 1)    ) ^ psw) << 4)) = wv0;
        *(uint2*)(base + ((((lg >> 1) + 2) ^ psw) << 4)) = wv1;
    }
    __syncthreads();   // 2

    // ---- conv1: 21 groups of 16 px over 18x18; 3 slots per wave; A from LDS (wc1s) ----
    int  p2c[3];
    int  pxb[3];   // b0s px index (20x20 domain) for tap 0
    bool inb[3];
#pragma unroll
    for (int i = 0; i < 3; ++i) {
        int g = wave + i * 8;
        if (g < 21) {
            int p2 = g * 16 + l15;
            int pc = p2 > 323 ? 323 : p2;
            p2c[i] = pc;
            int r2 = pc / 18, c2 = pc - r2 * 18;
            pxb[i] = r2 * 20 + c2;
            int gy1 = y0 - 1 + r2, gx1 = x0 - 1 + c2;
            inb[i] = (gy1 >= 0 && gy1 < HW && gx1 >= 0 && gx1 < HW);
        }
    }
    float4v acc1[3][4];
#pragma unroll
    for (int i = 0; i < 3; ++i)
#pragma unroll
        for (int mt = 0; mt < 4; ++mt) acc1[i][mt] = (float4v){0.f, 0.f, 0.f, 0.f};

    const int aoff = l15 * 64 + ((lg ^ ((l15 >> 1) & 3)) << 4);   // swizzled A-frag offset
#pragma unroll
    for (int tap = 0; tap < 9; ++tap) {
        const int ky = tap / 3, kx = tap - (tap / 3) * 3;
        const int po = ky * 20 + kx;
        short8 A[4];
#pragma unroll
        for (int mt = 0; mt < 4; ++mt)
            A[mt] = *(const short8*)(wc1s + tap * 4096 + mt * 1024 + aoff);
#pragma unroll
        for (int i = 0; i < 3; ++i) {
            int g = wave + i * 8;
            if (g < 21) {
                int px20 = pxb[i] + po;
                short8 Bf = *(const short8*)((const char*)b0s + px20 * 64 +
                                             ((lg ^ ((px20 >> 1) & 3)) << 4));
#pragma unroll
                for (int mt = 0; mt < 4; ++mt)
                    acc1[i][mt] = __builtin_amdgcn_mfma_f32_16x16x32_bf16(A[mt], Bf, acc1[i][mt], 0, 0, 0);
            }
        }
    }

    // ---- conv2 in-register: B-frag[kc] = bf16(acc1[2kc], acc1[2kc+1]); D[m=tap][n=px] ----
#pragma unroll
    for (int i = 0; i < 3; ++i) {
        int g = wave + i * 8;
        if (g < 21) {
            int pc = p2c[i];
            float4v acc2 = (float4v){0.f, 0.f, 0.f, 0.f};
#pragma unroll
            for (int kc = 0; kc < 2; ++kc) {
                uint4 dv;
                dv.x = pack2rnd(acc1[i][kc * 2][0],     acc1[i][kc * 2][1]);
                dv.y = pack2rnd(acc1[i][kc * 2][2],     acc1[i][kc * 2][3]);
                dv.z = pack2rnd(acc1[i][kc * 2 + 1][0], acc1[i][kc * 2 + 1][1]);
                dv.w = pack2rnd(acc1[i][kc * 2 + 1][2], acc1[i][kc * 2 + 1][3]);
                if (!inb[i]) { dv.x = 0; dv.y = 0; dv.z = 0; dv.w = 0; }
                short8 Bf = __builtin_bit_cast(short8, dv);
                acc2 = __builtin_amdgcn_mfma_f32_16x16x32_bf16(A2[kc], Bf, acc2, 0, 0, 0);
            }
            if (lg < 2) {
#pragma unroll
                for (int u = 0; u < 4; ++u) pbuf[pc * 13 + lg * 4 + u] = acc2[u];
            } else if (lg == 2) {
                pbuf[pc * 13 + 8] = acc2[0];
            }
        }
    }
    __syncthreads();   // 3

    // ---- reduction: out(r,c) = sum_tap pbuf[(r+ky)*18 + (c+kx)][tap] ----
    if (t < 256) {
        int r = t >> 4, c = t & 15;
        float o = 0.f;
#pragma unroll
        for (int ky = 0; ky < 3; ++ky)
#pragma unroll
            for (int kx = 0; kx < 3; ++kx)
                o += pbuf[((r + ky) * 18 + (c + kx)) * 13 + (ky * 3 + kx)];
        out[(size_t)b * HWHW + (y0 + r) * HW + (x0 + c)] = o;
    }
}

extern "C" void kernel_launch(void* const* d_in, const int* in_sizes, int n_in,
                              void* d_out, int out_size, void* d_ws, size_t ws_size,
                              hipStream_t stream)
{
    const float* x_meta = (const float*)d_in[0];
    const float* x      = (const float*)d_in[1];
    const float* w0     = (const float*)d_in[2];
    const float* b0     = (const float*)d_in[3];
    const float* w1     = (const float*)d_in[4];
    const float* b1     = (const float*)d_in[5];
    const float* w2     = (const float*)d_in[6];
    const float* b2     = (const float*)d_in[7];
    float* out = (float*)d_out;

    char* ws = (char*)d_ws;
    float* h1 = (float*)ws;                                                // @0       32768 B
    float* wc0 = (float*)(ws + 32768);                                     // @32768   18432 B
    unsigned short* wc1 = (unsigned short*)(ws + 51200);                   // @51200   589824 B
    unsigned short* wc2 = (unsigned short*)(ws + 641024);                  // @641024  18432 B

    mlp_kernel<<<dim3(16, 16), 256, 0, stream>>>(x_meta, w0, b0, w1, b1, h1);
    flat_kernel<<<603, 256, 0, stream>>>(h1, w2, b2, wc0, wc1, wc2);
    fused_conv_kernel<<<dim3(256, 16), 512, 0, stream>>>(x, wc0, wc1, wc2, out);
}